// Round 1
// baseline (1347.835 us; speedup 1.0000x reference)
//
#include <hip/hip_runtime.h>
#include <hip/hip_bf16.h>

// Sizes (fixed by setup_inputs): B=512, T=256, D=64, H=256, G=192, L=256.
// M = B*T = 131072 rows for all feedforward GEMMs.
#define MM 131072
#define TILE 64
#define BK 16

// ---------------------------------------------------------------------------
// Generic fp32 tiled GEMM: C[r, coff+c] = act(A[r,:]@W[:,c] + bias[c])
// A: M x K row-major (lda), W: K x N row-major (ldw), C row-major (ldc).
// ---------------------------------------------------------------------------
template <bool RELU, bool BIAS>
__global__ __launch_bounds__(256) void gemm_ff(
    const float* __restrict__ A, int lda,
    const float* __restrict__ W, int ldw,
    const float* __restrict__ bias,
    float* __restrict__ C, int ldc, int coff,
    int K)
{
    __shared__ __align__(16) float As[BK][TILE + 4]; // pad 68: 16B-aligned rows, spread banks
    __shared__ __align__(16) float Ws[BK][TILE];

    const int tx = threadIdx.x & 15;   // output col group (4 cols)
    const int ty = threadIdx.x >> 4;   // output row group (4 rows)
    const int row0 = blockIdx.x * TILE;
    const int col0 = blockIdx.y * TILE;

    float acc[4][4] = {};

    for (int k0 = 0; k0 < K; k0 += BK) {
        // A tile: 64 rows x 16 k   (lane: kk fast -> 16-float contiguous runs)
        {
            const int kk = threadIdx.x & 15;
            const int r  = threadIdx.x >> 4;   // 0..15
            #pragma unroll
            for (int rr = 0; rr < 4; ++rr) {
                const int row = row0 + r + rr * 16;
                As[kk][r + rr * 16] = A[(size_t)row * lda + k0 + kk];
            }
        }
        // W tile: 16 k x 64 cols  (lane: n fast -> fully coalesced)
        {
            const int n  = threadIdx.x & 63;
            const int kz = threadIdx.x >> 6;   // 0..3
            #pragma unroll
            for (int kq = 0; kq < 4; ++kq) {
                const int kk = kz + kq * 4;
                Ws[kk][n] = W[(size_t)(k0 + kk) * ldw + col0 + n];
            }
        }
        __syncthreads();
        #pragma unroll
        for (int kk = 0; kk < BK; ++kk) {
            const float4 a4 = *(const float4*)&As[kk][ty * 4];
            const float4 w4 = *(const float4*)&Ws[kk][tx * 4];
            const float av[4] = {a4.x, a4.y, a4.z, a4.w};
            const float wv[4] = {w4.x, w4.y, w4.z, w4.w};
            #pragma unroll
            for (int i = 0; i < 4; ++i)
                #pragma unroll
                for (int j = 0; j < 4; ++j)
                    acc[i][j] += av[i] * wv[j];
        }
        __syncthreads();
    }

    #pragma unroll
    for (int i = 0; i < 4; ++i) {
        const int r = row0 + ty * 4 + i;
        #pragma unroll
        for (int j = 0; j < 4; ++j) {
            const int c = col0 + tx * 4 + j;
            float v = acc[i][j];
            if (BIAS) v += bias[c];
            if (RELU) v = fmaxf(v, 0.0f);
            C[(size_t)r * ldc + coff + c] = v;
        }
    }
}

// ---------------------------------------------------------------------------
// Bu = [u | v] @ WB, written SHIFTED: row r=(b*256+t) -> y_pred slot t+1.
// Rows with t==255 are skipped (Bu[:, T-1] unused; writing would clobber
// the next batch-row's slot 0 which holds y0).
// ---------------------------------------------------------------------------
__global__ __launch_bounds__(256) void gemm_bu(
    const float* __restrict__ U,   // M x 64
    const float* __restrict__ V,   // M x 192 (compact)
    const float* __restrict__ WB,  // 256 x 256
    float* __restrict__ out2)      // y_pred region (B*T*L)
{
    __shared__ __align__(16) float As[BK][TILE + 4];
    __shared__ __align__(16) float Ws[BK][TILE];

    const int tx = threadIdx.x & 15;
    const int ty = threadIdx.x >> 4;
    const int row0 = blockIdx.x * TILE;
    const int col0 = blockIdx.y * TILE;

    float acc[4][4] = {};

    for (int k0 = 0; k0 < 256; k0 += BK) {
        {
            const int kk = threadIdx.x & 15;
            const int r  = threadIdx.x >> 4;
            #pragma unroll
            for (int rr = 0; rr < 4; ++rr) {
                const int row = row0 + r + rr * 16;
                float av;
                if (k0 < 64) av = U[(size_t)row * 64 + k0 + kk];
                else         av = V[(size_t)row * 192 + (k0 - 64) + kk];
                As[kk][r + rr * 16] = av;
            }
        }
        {
            const int n  = threadIdx.x & 63;
            const int kz = threadIdx.x >> 6;
            #pragma unroll
            for (int kq = 0; kq < 4; ++kq) {
                const int kk = kz + kq * 4;
                Ws[kk][n] = WB[(size_t)(k0 + kk) * 256 + col0 + n];
            }
        }
        __syncthreads();
        #pragma unroll
        for (int kk = 0; kk < BK; ++kk) {
            const float4 a4 = *(const float4*)&As[kk][ty * 4];
            const float4 w4 = *(const float4*)&Ws[kk][tx * 4];
            const float av[4] = {a4.x, a4.y, a4.z, a4.w};
            const float wv[4] = {w4.x, w4.y, w4.z, w4.w};
            #pragma unroll
            for (int i = 0; i < 4; ++i)
                #pragma unroll
                for (int j = 0; j < 4; ++j)
                    acc[i][j] += av[i] * wv[j];
        }
        __syncthreads();
    }

    #pragma unroll
    for (int i = 0; i < 4; ++i) {
        const int r = row0 + ty * 4 + i;
        if ((r & 255) != 255) {
            #pragma unroll
            for (int j = 0; j < 4; ++j) {
                const int c = col0 + tx * 4 + j;
                out2[(size_t)(r + 1) * 256 + c] = acc[i][j];
            }
        }
    }
}

// copy x (M x 64) into y columns 0..63 (ldc 256), float4-vectorized
__global__ __launch_bounds__(256) void copy_x(const float* __restrict__ x,
                                              float* __restrict__ y)
{
    const int i = blockIdx.x * blockDim.x + threadIdx.x; // 0 .. M*16-1
    const int r = i >> 4, q = i & 15;
    const float4 v = ((const float4*)(x + (size_t)r * 64))[q];
    ((float4*)(y + (size_t)r * 256))[q] = v;
}

// y0 = y[:,0,:] -> y_pred slot 0
__global__ __launch_bounds__(256) void y0copy(const float* __restrict__ y,
                                              float* __restrict__ yp)
{
    const int i = blockIdx.x * blockDim.x + threadIdx.x; // 0..131071
    const int b = i >> 8, j = i & 255;
    yp[(size_t)b * 65536 + j] = y[(size_t)b * 65536 + j];
}

// ---------------------------------------------------------------------------
// Sequential scan: y_t = y_{t-1} @ WK + bK + Bu_{t-1}, in-place in yp.
// Slot t holds Bu[b, t-1] on entry, y_t on exit. One block = 2 batch rows.
// 1024 threads: j = tid&255 (output col), a = tid>>8 (4-way K split).
// WK held in registers (64 fp32 per thread).
// ---------------------------------------------------------------------------
__global__ __launch_bounds__(1024) void scan_kernel(
    const float* __restrict__ WK, const float* __restrict__ bK,
    float* __restrict__ yp)
{
    __shared__ __align__(16) float carry[2][256];
    __shared__ __align__(16) float partials[3][2][256];

    const int tid = threadIdx.x;
    const int j = tid & 255;
    const int a = tid >> 8;
    const int b0 = blockIdx.x * 2;

    float wk[64];
    #pragma unroll
    for (int ii = 0; ii < 64; ++ii)
        wk[ii] = WK[(size_t)(a * 64 + ii) * 256 + j];
    const float bkj = bK[j];

    if (a == 0) {
        carry[0][j] = yp[(size_t)(b0 + 0) * 65536 + j];
        carry[1][j] = yp[(size_t)(b0 + 1) * 65536 + j];
    }
    __syncthreads();

    for (int t = 1; t < 256; ++t) {
        float bu0 = 0.0f, bu1 = 0.0f;
        if (a == 0) {
            bu0 = yp[(size_t)(b0 + 0) * 65536 + (size_t)t * 256 + j];
            bu1 = yp[(size_t)(b0 + 1) * 65536 + (size_t)t * 256 + j];
        }
        float p0 = 0.0f, p1 = 0.0f;
        const float4* c0 = (const float4*)&carry[0][a * 64];
        const float4* c1 = (const float4*)&carry[1][a * 64];
        #pragma unroll
        for (int q = 0; q < 16; ++q) {
            const float4 cv0 = c0[q];
            const float4 cv1 = c1[q];
            p0 += cv0.x * wk[q*4+0] + cv0.y * wk[q*4+1]
                + cv0.z * wk[q*4+2] + cv0.w * wk[q*4+3];
            p1 += cv1.x * wk[q*4+0] + cv1.y * wk[q*4+1]
                + cv1.z * wk[q*4+2] + cv1.w * wk[q*4+3];
        }
        if (a != 0) {
            partials[a - 1][0][j] = p0;
            partials[a - 1][1][j] = p1;
        }
        __syncthreads();
        if (a == 0) {
            const float r0 = p0 + partials[0][0][j] + partials[1][0][j]
                           + partials[2][0][j] + bkj + bu0;
            const float r1 = p1 + partials[0][1][j] + partials[1][1][j]
                           + partials[2][1][j] + bkj + bu1;
            carry[0][j] = r0;
            carry[1][j] = r1;
            yp[(size_t)(b0 + 0) * 65536 + (size_t)t * 256 + j] = r0;
            yp[(size_t)(b0 + 1) * 65536 + (size_t)t * 256 + j] = r1;
        }
        __syncthreads();
    }
}

// ---------------------------------------------------------------------------
extern "C" void kernel_launch(void* const* d_in, const int* in_sizes, int n_in,
                              void* d_out, int out_size, void* d_ws, size_t ws_size,
                              hipStream_t stream)
{
    const float* x   = (const float*)d_in[0];
    const float* u   = (const float*)d_in[1];
    const float* Wx1 = (const float*)d_in[2];
    const float* bx1 = (const float*)d_in[3];
    const float* Wx2 = (const float*)d_in[4];
    const float* bx2 = (const float*)d_in[5];
    const float* Wx3 = (const float*)d_in[6];
    const float* Wu1 = (const float*)d_in[7];
    const float* bu1 = (const float*)d_in[8];
    const float* Wu2 = (const float*)d_in[9];
    const float* WB  = (const float*)d_in[10];
    const float* WK  = (const float*)d_in[11];
    const float* bK  = (const float*)d_in[12];

    float* y  = (float*)d_out;                   // output 0: (B,T,L)
    float* yp = y + (size_t)MM * 256;            // output 1: (B,T,L), also temp
    float* ta = (float*)d_ws;                    // 131072 x 256 f32 scratch (134 MB)

    dim3 blk(256);

    // x path: g1 -> yp ; g2 -> ta ; g3 -> y[:, 64:256]
    gemm_ff<true,  true ><<<dim3(MM / TILE, 4), blk, 0, stream>>>(x,  64, Wx1, 256, bx1, yp, 256, 0, 64);
    gemm_ff<true,  true ><<<dim3(MM / TILE, 4), blk, 0, stream>>>(yp, 256, Wx2, 256, bx2, ta, 256, 0, 256);
    gemm_ff<false, false><<<dim3(MM / TILE, 3), blk, 0, stream>>>(ta, 256, Wx3, 192, nullptr, y, 256, 64, 256);
    copy_x<<<(MM * 16) / 256, blk, 0, stream>>>(x, y);

    // u path: v1 -> yp ; v -> ta (compact 192) ; Bu -> yp slots t+1
    gemm_ff<true,  true ><<<dim3(MM / TILE, 4), blk, 0, stream>>>(u,  64, Wu1, 256, bu1, yp, 256, 0, 64);
    gemm_ff<false, false><<<dim3(MM / TILE, 3), blk, 0, stream>>>(yp, 256, Wu2, 192, nullptr, ta, 192, 0, 256);
    gemm_bu<<<dim3(MM / TILE, 4), blk, 0, stream>>>(u, ta, WB, yp);

    // y0 -> slot 0, then the recurrence (in-place in yp)
    y0copy<<<512, blk, 0, stream>>>(y, yp);
    scan_kernel<<<256, 1024, 0, stream>>>(WK, bK, yp);
}

// Round 2
// 632.901 us; speedup vs baseline: 2.1296x; 2.1296x over previous
//
#include <hip/hip_runtime.h>
#include <hip/hip_bf16.h>

#define MM 131072

typedef __attribute__((ext_vector_type(8))) short short8;
typedef __attribute__((ext_vector_type(4))) float f32x4;

#define GLP(p) (const __attribute__((address_space(1))) void*)(p)
#define LDSP(p) (__attribute__((address_space(3))) void*)(p)

// ---------------------------------------------------------------------------
// fp32 -> bf16 elementwise (4 per thread)
// ---------------------------------------------------------------------------
__global__ __launch_bounds__(256) void conv_bf16(const float* __restrict__ src,
                                                 __hip_bfloat16* __restrict__ dst)
{
    const int i = blockIdx.x * 256 + threadIdx.x;
    const float4 v = ((const float4*)src)[i];
    union { __hip_bfloat16 h[4]; uint2 u; } p;
    p.h[0] = __float2bfloat16(v.x);
    p.h[1] = __float2bfloat16(v.y);
    p.h[2] = __float2bfloat16(v.z);
    p.h[3] = __float2bfloat16(v.w);
    ((uint2*)dst)[i] = p.u;
}

// W (K x N, f32) -> WT (N x K, bf16)
__global__ __launch_bounds__(256) void wtrans(const float* __restrict__ W,
                                              __hip_bfloat16* __restrict__ WT,
                                              int K, int N)
{
    const int i = blockIdx.x * 256 + threadIdx.x;
    if (i >= K * N) return;
    const int n = i / K, k = i - n * K;
    WT[i] = __float2bfloat16(W[(size_t)k * N + n]);
}

// ---------------------------------------------------------------------------
// bf16 MFMA GEMM, 128x128 tile, 4 waves (2x2), 4x4 16x16x32 frags per wave.
// A: M x K bf16 row-major (optionally concat of A|A2 split at ksplit).
// WT: N x K bf16 row-major (pre-transposed weights).
// EPI: 0 = bias+relu -> bf16 ; 1 = plain -> bf16 ;
//      2 = plain -> f32 with col offset ; 3 = Bu: f32, row-shifted +1, skip t==255
// ---------------------------------------------------------------------------
template <int EPI>
__global__ __launch_bounds__(256) void mgemm(
    const __hip_bfloat16* __restrict__ A, int lda,
    const __hip_bfloat16* __restrict__ A2, int lda2, int ksplit,
    const __hip_bfloat16* __restrict__ WT, int K, int Ncols,
    const float* __restrict__ bias,
    void* __restrict__ Cout, int ldc, int coff)
{
    __shared__ __align__(16) __hip_bfloat16 As[128 * 32];
    __shared__ __align__(16) __hip_bfloat16 Bs[128 * 32];

    const int tid  = threadIdx.x;
    const int lane = tid & 63;
    const int wid  = tid >> 6;
    const int wm   = wid & 1;        // wave row (2)
    const int wn   = wid >> 1;       // wave col (2)
    const int row0 = blockIdx.x * 128;
    int col0 = blockIdx.y * 128;
    if (col0 + 128 > Ncols) col0 = Ncols - 128;   // overlap tiles for N=192

    f32x4 acc[4][4];
    #pragma unroll
    for (int mi = 0; mi < 4; ++mi)
        #pragma unroll
        for (int ni = 0; ni < 4; ++ni)
            acc[mi][ni] = {0.f, 0.f, 0.f, 0.f};

    const int rlow = lane & 15;
    const int c    = lane >> 4;      // logical 8-elem k-chunk (0..3)

    for (int k0 = 0; k0 < K; k0 += 32) {
        // uniform A-source select (Bu concat: k0<64 from u, else from v)
        const __hip_bfloat16* Ab; int Al, kk;
        if (k0 < ksplit) { Ab = A;  Al = lda;  kk = k0; }
        else             { Ab = A2; Al = lda2; kk = k0 - ksplit; }

        // stage 128x32 tiles; LDS linear, source pre-swizzled: chunk ^= (row>>1)&3
        #pragma unroll
        for (int r = 0; r < 2; ++r) {
            const int i   = r * 256 + tid;          // 0..511
            const int row = i >> 2;
            const int cl  = (i & 3) ^ ((row >> 1) & 3);
            const __hip_bfloat16* sa = Ab + (size_t)(row0 + row) * Al + kk + cl * 8;
            __builtin_amdgcn_global_load_lds(GLP(sa), LDSP(As + i * 8), 16, 0, 0);
            const __hip_bfloat16* sb = WT + (size_t)(col0 + row) * K + k0 + cl * 8;
            __builtin_amdgcn_global_load_lds(GLP(sb), LDSP(Bs + i * 8), 16, 0, 0);
        }
        __syncthreads();

        short8 af[4], bfr[4];
        #pragma unroll
        for (int mi = 0; mi < 4; ++mi) {
            const int row  = wm * 64 + mi * 16 + rlow;
            const int phys = c ^ ((row >> 1) & 3);
            af[mi] = *(const short8*)((const char*)As + row * 64 + phys * 16);
        }
        #pragma unroll
        for (int ni = 0; ni < 4; ++ni) {
            const int row  = wn * 64 + ni * 16 + rlow;
            const int phys = c ^ ((row >> 1) & 3);
            bfr[ni] = *(const short8*)((const char*)Bs + row * 64 + phys * 16);
        }
        #pragma unroll
        for (int mi = 0; mi < 4; ++mi)
            #pragma unroll
            for (int ni = 0; ni < 4; ++ni)
                acc[mi][ni] = __builtin_amdgcn_mfma_f32_16x16x32_bf16(
                    af[mi], bfr[ni], acc[mi][ni], 0, 0, 0);
        __syncthreads();
    }

    // epilogue: C/D layout col=lane&15, row=(lane>>4)*4+q
    const int q4 = lane >> 4;
    #pragma unroll
    for (int ni = 0; ni < 4; ++ni) {
        const int col = col0 + wn * 64 + ni * 16 + rlow;
        float bv = 0.f;
        if (EPI == 0) bv = bias[col];
        #pragma unroll
        for (int mi = 0; mi < 4; ++mi) {
            #pragma unroll
            for (int q = 0; q < 4; ++q) {
                const int row = row0 + wm * 64 + mi * 16 + q4 * 4 + q;
                float v = acc[mi][ni][q];
                if (EPI == 0) v = fmaxf(v + bv, 0.f);
                if (EPI == 0 || EPI == 1) {
                    ((__hip_bfloat16*)Cout)[(size_t)row * ldc + col] = __float2bfloat16(v);
                } else if (EPI == 2) {
                    ((float*)Cout)[(size_t)row * ldc + coff + col] = v;
                } else {
                    if ((row & 255) != 255)
                        ((float*)Cout)[(size_t)(row + 1) * 256 + col] = v;
                }
            }
        }
    }
}

// copy x (M x 64) into y columns 0..63 (ldc 256)
__global__ __launch_bounds__(256) void copy_x(const float* __restrict__ x,
                                              float* __restrict__ y)
{
    const int i = blockIdx.x * blockDim.x + threadIdx.x;
    const int r = i >> 4, q = i & 15;
    const float4 v = ((const float4*)(x + (size_t)r * 64))[q];
    ((float4*)(y + (size_t)r * 256))[q] = v;
}

// y0 = y[:,0,:] -> y_pred slot 0
__global__ __launch_bounds__(256) void y0copy(const float* __restrict__ y,
                                              float* __restrict__ yp)
{
    const int i = blockIdx.x * blockDim.x + threadIdx.x;
    const int b = i >> 8, j = i & 255;
    yp[(size_t)b * 65536 + j] = y[(size_t)b * 65536 + j];
}

// ---------------------------------------------------------------------------
// Sequential scan: y_t = y_{t-1} @ WK + bK + Bu_{t-1}, in-place in yp.
// ---------------------------------------------------------------------------
__global__ __launch_bounds__(1024) void scan_kernel(
    const float* __restrict__ WK, const float* __restrict__ bK,
    float* __restrict__ yp)
{
    __shared__ __align__(16) float carry[2][256];
    __shared__ __align__(16) float partials[3][2][256];

    const int tid = threadIdx.x;
    const int j = tid & 255;
    const int a = tid >> 8;
    const int b0 = blockIdx.x * 2;

    float wk[64];
    #pragma unroll
    for (int ii = 0; ii < 64; ++ii)
        wk[ii] = WK[(size_t)(a * 64 + ii) * 256 + j];
    const float bkj = bK[j];

    if (a == 0) {
        carry[0][j] = yp[(size_t)(b0 + 0) * 65536 + j];
        carry[1][j] = yp[(size_t)(b0 + 1) * 65536 + j];
    }
    __syncthreads();

    for (int t = 1; t < 256; ++t) {
        float bu0 = 0.0f, bu1 = 0.0f;
        if (a == 0) {
            bu0 = yp[(size_t)(b0 + 0) * 65536 + (size_t)t * 256 + j];
            bu1 = yp[(size_t)(b0 + 1) * 65536 + (size_t)t * 256 + j];
        }
        float p0 = 0.0f, p1 = 0.0f;
        const float4* c0 = (const float4*)&carry[0][a * 64];
        const float4* c1 = (const float4*)&carry[1][a * 64];
        #pragma unroll
        for (int q = 0; q < 16; ++q) {
            const float4 cv0 = c0[q];
            const float4 cv1 = c1[q];
            p0 += cv0.x * wk[q*4+0] + cv0.y * wk[q*4+1]
                + cv0.z * wk[q*4+2] + cv0.w * wk[q*4+3];
            p1 += cv1.x * wk[q*4+0] + cv1.y * wk[q*4+1]
                + cv1.z * wk[q*4+2] + cv1.w * wk[q*4+3];
        }
        if (a != 0) {
            partials[a - 1][0][j] = p0;
            partials[a - 1][1][j] = p1;
        }
        __syncthreads();
        if (a == 0) {
            const float r0 = p0 + partials[0][0][j] + partials[1][0][j]
                           + partials[2][0][j] + bkj + bu0;
            const float r1 = p1 + partials[0][1][j] + partials[1][1][j]
                           + partials[2][1][j] + bkj + bu1;
            carry[0][j] = r0;
            carry[1][j] = r1;
            yp[(size_t)(b0 + 0) * 65536 + (size_t)t * 256 + j] = r0;
            yp[(size_t)(b0 + 1) * 65536 + (size_t)t * 256 + j] = r1;
        }
        __syncthreads();
    }
}

// ---------------------------------------------------------------------------
extern "C" void kernel_launch(void* const* d_in, const int* in_sizes, int n_in,
                              void* d_out, int out_size, void* d_ws, size_t ws_size,
                              hipStream_t stream)
{
    const float* x   = (const float*)d_in[0];
    const float* u   = (const float*)d_in[1];
    const float* Wx1 = (const float*)d_in[2];
    const float* bx1 = (const float*)d_in[3];
    const float* Wx2 = (const float*)d_in[4];
    const float* bx2 = (const float*)d_in[5];
    const float* Wx3 = (const float*)d_in[6];
    const float* Wu1 = (const float*)d_in[7];
    const float* bu1 = (const float*)d_in[8];
    const float* Wu2 = (const float*)d_in[9];
    const float* WB  = (const float*)d_in[10];
    const float* WK  = (const float*)d_in[11];
    const float* bK  = (const float*)d_in[12];

    float* y  = (float*)d_out;                  // output 0
    float* yp = y + (size_t)MM * 256;           // output 1, doubles as bf16 scratch

    char* ws = (char*)d_ws;
    __hip_bfloat16* x_bf  = (__hip_bfloat16*)(ws);                 // 16.8 MB
    __hip_bfloat16* u_bf  = (__hip_bfloat16*)(ws + 16777216);      // 16.8 MB
    __hip_bfloat16* wTb   = (__hip_bfloat16*)(ws + 33554432);      // 512 KB
    __hip_bfloat16* Wx1T = wTb;              // 256x64
    __hip_bfloat16* Wx2T = wTb + 16384;      // 256x256
    __hip_bfloat16* Wx3T = wTb + 81920;      // 192x256
    __hip_bfloat16* Wu1T = wTb + 131072;     // 256x64
    __hip_bfloat16* Wu2T = wTb + 147456;     // 192x256
    __hip_bfloat16* WBT  = wTb + 196608;     // 256x256
    __hip_bfloat16* t2    = (__hip_bfloat16*)(ws + 34078720);      // 67 MB

    __hip_bfloat16* g1_bf = (__hip_bfloat16*)yp;                       // 67 MB
    __hip_bfloat16* v1_bf = (__hip_bfloat16*)((char*)yp + 67108864);   // 67 MB

    dim3 blk(256);

    // conversions
    conv_bf16<<<8192, blk, 0, stream>>>(x, x_bf);   // 131072*64/4 = 2.1M thr
    conv_bf16<<<8192, blk, 0, stream>>>(u, u_bf);
    wtrans<<<64,  blk, 0, stream>>>(Wx1, Wx1T, 64, 256);
    wtrans<<<256, blk, 0, stream>>>(Wx2, Wx2T, 256, 256);
    wtrans<<<192, blk, 0, stream>>>(Wx3, Wx3T, 256, 192);
    wtrans<<<64,  blk, 0, stream>>>(Wu1, Wu1T, 64, 256);
    wtrans<<<192, blk, 0, stream>>>(Wu2, Wu2T, 256, 192);
    wtrans<<<256, blk, 0, stream>>>(WB,  WBT,  256, 256);

    // x path
    mgemm<0><<<dim3(1024, 2), blk, 0, stream>>>(x_bf, 64, nullptr, 0, 64,
        Wx1T, 64, 256, bx1, g1_bf, 256, 0);
    mgemm<0><<<dim3(1024, 2), blk, 0, stream>>>(g1_bf, 256, nullptr, 0, 256,
        Wx2T, 256, 256, bx2, t2, 256, 0);
    mgemm<2><<<dim3(1024, 2), blk, 0, stream>>>(t2, 256, nullptr, 0, 256,
        Wx3T, 256, 192, nullptr, y, 256, 64);
    copy_x<<<(MM * 16) / 256, blk, 0, stream>>>(x, y);

    // u path
    mgemm<0><<<dim3(1024, 2), blk, 0, stream>>>(u_bf, 64, nullptr, 0, 64,
        Wu1T, 64, 256, bu1, v1_bf, 256, 0);
    mgemm<1><<<dim3(1024, 2), blk, 0, stream>>>(v1_bf, 256, nullptr, 0, 256,
        Wu2T, 256, 192, nullptr, t2, 192, 0);
    mgemm<3><<<dim3(1024, 2), blk, 0, stream>>>(u_bf, 64, t2, 192, 64,
        WBT, 256, 256, nullptr, yp, 256, 0);

    // recurrence
    y0copy<<<512, blk, 0, stream>>>(y, yp);
    scan_kernel<<<256, 1024, 0, stream>>>(WK, bK, yp);
}

// Round 4
// 609.453 us; speedup vs baseline: 2.2115x; 1.0385x over previous
//
#include <hip/hip_runtime.h>
#include <hip/hip_bf16.h>

#define MM 131072

typedef __attribute__((ext_vector_type(8))) short short8;
typedef __attribute__((ext_vector_type(4))) float f32x4;

#define GLP(p) (const __attribute__((address_space(1))) void*)(p)
#define LDSP(p) (__attribute__((address_space(3))) void*)(p)

static __device__ __forceinline__ unsigned short f2bf(float f) {
    union { float f; unsigned int u; } v; v.f = f;
    unsigned int r = v.u + 0x7FFF + ((v.u >> 16) & 1);  // RNE
    return (unsigned short)(r >> 16);
}
static __device__ __forceinline__ float bf2f(unsigned short h) {
    union { float f; unsigned int u; } v; v.u = ((unsigned int)h) << 16;
    return v.f;
}

// ---------------------------------------------------------------------------
// fused fp32 -> bf16 conversion for x and u (4 f32 per thread)
// ---------------------------------------------------------------------------
__global__ __launch_bounds__(256) void conv2_bf16(
    const float* __restrict__ x, const float* __restrict__ u,
    __hip_bfloat16* __restrict__ xb, __hip_bfloat16* __restrict__ ub)
{
    int i = blockIdx.x * 256 + threadIdx.x;      // 0 .. 4194303
    const float* s; __hip_bfloat16* d; int j;
    if (i < 2097152) { s = x; d = xb; j = i; }
    else             { s = u; d = ub; j = i - 2097152; }
    const float4 v = ((const float4*)s)[j];
    union { unsigned short h[4]; uint2 u2; } p;
    p.h[0] = f2bf(v.x); p.h[1] = f2bf(v.y);
    p.h[2] = f2bf(v.z); p.h[3] = f2bf(v.w);
    ((uint2*)d)[j] = p.u2;
}

// fused W (K x N, f32) -> WT (N x K, bf16) for all 6 weights
__global__ __launch_bounds__(256) void wtrans_all(
    const float* __restrict__ W0, const float* __restrict__ W1,
    const float* __restrict__ W2, const float* __restrict__ W3,
    const float* __restrict__ W4, const float* __restrict__ W5,
    __hip_bfloat16* __restrict__ T0, __hip_bfloat16* __restrict__ T1,
    __hip_bfloat16* __restrict__ T2, __hip_bfloat16* __restrict__ T3,
    __hip_bfloat16* __restrict__ T4, __hip_bfloat16* __restrict__ T5)
{
    const int b = blockIdx.x;
    const float* W; __hip_bfloat16* T; int K, N, i0;
    if      (b < 64)  { W = W0; T = T0; K = 64;  N = 256; i0 = b; }
    else if (b < 320) { W = W1; T = T1; K = 256; N = 256; i0 = b - 64; }
    else if (b < 512) { W = W2; T = T2; K = 256; N = 192; i0 = b - 320; }
    else if (b < 576) { W = W3; T = T3; K = 64;  N = 256; i0 = b - 512; }
    else if (b < 768) { W = W4; T = T4; K = 256; N = 192; i0 = b - 576; }
    else              { W = W5; T = T5; K = 256; N = 256; i0 = b - 768; }
    const int i = i0 * 256 + threadIdx.x;
    if (i < K * N) {
        const int n = i / K, k = i - n * K;
        T[i] = __float2bfloat16(W[(size_t)k * N + n]);
    }
}

// ---------------------------------------------------------------------------
// bf16 MFMA GEMM, 128x128 tile, 4 waves (2x2), 4x4 16x16x32 frags per wave.
// EPI: 0 = bias+relu -> bf16 ; 1 = plain -> bf16 ;
//      2 = plain -> f32 with col offset ; 3 = Bu: f32, row-shifted +1, skip t==255
// ---------------------------------------------------------------------------
template <int EPI>
__global__ __launch_bounds__(256) void mgemm(
    const __hip_bfloat16* __restrict__ A, int lda,
    const __hip_bfloat16* __restrict__ A2, int lda2, int ksplit,
    const __hip_bfloat16* __restrict__ WT, int K, int Ncols,
    const float* __restrict__ bias,
    void* __restrict__ Cout, int ldc, int coff)
{
    __shared__ __align__(16) __hip_bfloat16 As[128 * 32];
    __shared__ __align__(16) __hip_bfloat16 Bs[128 * 32];

    const int tid  = threadIdx.x;
    const int lane = tid & 63;
    const int wid  = tid >> 6;
    const int wm   = wid & 1;
    const int wn   = wid >> 1;
    const int row0 = blockIdx.x * 128;
    int col0 = blockIdx.y * 128;
    if (col0 + 128 > Ncols) col0 = Ncols - 128;

    f32x4 acc[4][4];
    #pragma unroll
    for (int mi = 0; mi < 4; ++mi)
        #pragma unroll
        for (int ni = 0; ni < 4; ++ni)
            acc[mi][ni] = {0.f, 0.f, 0.f, 0.f};

    const int rlow = lane & 15;
    const int c    = lane >> 4;

    for (int k0 = 0; k0 < K; k0 += 32) {
        const __hip_bfloat16* Ab; int Al, kk;
        if (k0 < ksplit) { Ab = A;  Al = lda;  kk = k0; }
        else             { Ab = A2; Al = lda2; kk = k0 - ksplit; }

        #pragma unroll
        for (int r = 0; r < 2; ++r) {
            const int i   = r * 256 + tid;
            const int row = i >> 2;
            const int cl  = (i & 3) ^ ((row >> 1) & 3);
            const __hip_bfloat16* sa = Ab + (size_t)(row0 + row) * Al + kk + cl * 8;
            __builtin_amdgcn_global_load_lds(GLP(sa), LDSP(As + i * 8), 16, 0, 0);
            const __hip_bfloat16* sb = WT + (size_t)(col0 + row) * K + k0 + cl * 8;
            __builtin_amdgcn_global_load_lds(GLP(sb), LDSP(Bs + i * 8), 16, 0, 0);
        }
        __syncthreads();

        short8 af[4], bfr[4];
        #pragma unroll
        for (int mi = 0; mi < 4; ++mi) {
            const int row  = wm * 64 + mi * 16 + rlow;
            const int phys = c ^ ((row >> 1) & 3);
            af[mi] = *(const short8*)((const char*)As + row * 64 + phys * 16);
        }
        #pragma unroll
        for (int ni = 0; ni < 4; ++ni) {
            const int row  = wn * 64 + ni * 16 + rlow;
            const int phys = c ^ ((row >> 1) & 3);
            bfr[ni] = *(const short8*)((const char*)Bs + row * 64 + phys * 16);
        }
        #pragma unroll
        for (int mi = 0; mi < 4; ++mi)
            #pragma unroll
            for (int ni = 0; ni < 4; ++ni)
                acc[mi][ni] = __builtin_amdgcn_mfma_f32_16x16x32_bf16(
                    af[mi], bfr[ni], acc[mi][ni], 0, 0, 0);
        __syncthreads();
    }

    const int q4 = lane >> 4;
    #pragma unroll
    for (int ni = 0; ni < 4; ++ni) {
        const int col = col0 + wn * 64 + ni * 16 + rlow;
        float bv = 0.f;
        if (EPI == 0) bv = bias[col];
        #pragma unroll
        for (int mi = 0; mi < 4; ++mi) {
            #pragma unroll
            for (int q = 0; q < 4; ++q) {
                const int row = row0 + wm * 64 + mi * 16 + q4 * 4 + q;
                float v = acc[mi][ni][q];
                if (EPI == 0) v = fmaxf(v + bv, 0.f);
                if (EPI == 0 || EPI == 1) {
                    ((__hip_bfloat16*)Cout)[(size_t)row * ldc + col] = __float2bfloat16(v);
                } else if (EPI == 2) {
                    ((float*)Cout)[(size_t)row * ldc + coff + col] = v;
                } else {
                    if ((row & 255) != 255)
                        ((float*)Cout)[(size_t)(row + 1) * 256 + col] = v;
                }
            }
        }
    }
}

// copy x (M x 64) into y columns 0..63
__global__ __launch_bounds__(256) void copy_x(const float* __restrict__ x,
                                              float* __restrict__ y)
{
    const int i = blockIdx.x * blockDim.x + threadIdx.x;
    const int r = i >> 4, q = i & 15;
    const float4 v = ((const float4*)(x + (size_t)r * 64))[q];
    ((float4*)(y + (size_t)r * 256))[q] = v;
}

// y0 = y[:,0,:] -> y_pred slot 0
__global__ __launch_bounds__(256) void y0copy(const float* __restrict__ y,
                                              float* __restrict__ yp)
{
    const int i = blockIdx.x * blockDim.x + threadIdx.x;
    const int b = i >> 8, j = i & 255;
    yp[(size_t)b * 65536 + j] = y[(size_t)b * 65536 + j];
}

// ---------------------------------------------------------------------------
// MFMA scan: y_t = y_{t-1}@WK + bK + Bu_{t-1}, in-place in yp.
// 32 blocks x 8 waves; block owns 16 batch rows; wave owns 32 cols.
// WK register-resident as bf16 hi/lo B-fragments (3-pass split product keeps
// carry at ~fp32 accuracy). Carry in LDS bf16 hi/lo, double-buffered,
// XOR-swizzled on the FULL byte address (round-3 bug: swizzle applied before
// adding kc*64 corrupted bit 6 for half the lanes).
// ---------------------------------------------------------------------------
__global__ __launch_bounds__(512, 2) void scan_mfma(
    const float* __restrict__ WK, const float* __restrict__ bK,
    float* __restrict__ yp)
{
    __shared__ __align__(16) __hip_bfloat16 cbuf[2][2][16 * 256]; // [buf][hi/lo]

    const int tid  = threadIdx.x;
    const int lane = tid & 63;
    const int wid  = tid >> 6;          // 0..7
    const int r0   = blockIdx.x * 16;   // batch rows
    const int col0 = wid * 32;          // wave's 32 output cols
    const int rlow = lane & 15;
    const int kg   = lane >> 4;         // 0..3

    // ---- WK B-fragments (one-time gather): elem i = WK[k0+i][col]
    short8 wh[2][8], wl[2][8];
    float bkv[2];
    #pragma unroll
    for (int tile = 0; tile < 2; ++tile) {
        const int col = col0 + tile * 16 + rlow;
        bkv[tile] = bK[col];
        for (int kc = 0; kc < 8; ++kc) {
            const int k0 = kc * 32 + kg * 8;
            short8 h, l;
            for (int i = 0; i < 8; ++i) {
                const float w = WK[(size_t)(k0 + i) * 256 + col];
                const unsigned short hb = f2bf(w);
                const unsigned short lb = f2bf(w - bf2f(hb));
                h[i] = (short)hb;
                l[i] = (short)lb;
            }
            wh[tile][kc] = h;
            wl[tile][kc] = l;
        }
    }

    // ---- init carry = y0 (yp slot 0) into buf 0
    {
        const int row = tid >> 5;          // 0..15
        const int c8  = (tid & 31) * 8;    // col start
        const float* src = yp + (size_t)(r0 + row) * 65536 + c8;
        const float4 a = *(const float4*)src;
        const float4 b = *(const float4*)(src + 4);
        const float vals[8] = {a.x, a.y, a.z, a.w, b.x, b.y, b.z, b.w};
        short8 h8, l8;
        #pragma unroll
        for (int i = 0; i < 8; ++i) {
            const unsigned short hb = f2bf(vals[i]);
            h8[i] = (short)hb;
            l8[i] = (short)f2bf(vals[i] - bf2f(hb));
        }
        const int byte = (row * 512 + c8 * 2) ^ ((row & 7) << 4);
        *(short8*)((char*)&cbuf[0][0][0] + byte) = h8;
        *(short8*)((char*)&cbuf[0][1][0] + byte) = l8;
    }
    __syncthreads();

    // ---- prefetch Bu for t=1
    float bu_c[2][4];
    #pragma unroll
    for (int tile = 0; tile < 2; ++tile)
        #pragma unroll
        for (int q = 0; q < 4; ++q)
            bu_c[tile][q] = yp[(size_t)(r0 + kg * 4 + q) * 65536 + 256 + (col0 + tile * 16 + rlow)];

    int cur = 0;
    const int rswz = (rlow & 7) << 4;

    for (int t = 1; t < 256; ++t) {
        // A-fragments (carry) + 3-pass MFMA, 6 independent accumulation chains
        f32x4 aHH[2], aHL[2], aLH[2];
        #pragma unroll
        for (int tile = 0; tile < 2; ++tile) {
            aHH[tile] = {0.f, 0.f, 0.f, 0.f};
            aHL[tile] = {0.f, 0.f, 0.f, 0.f};
            aLH[tile] = {0.f, 0.f, 0.f, 0.f};
        }
        const char* hbase = (const char*)&cbuf[cur][0][0];
        const char* lbase = (const char*)&cbuf[cur][1][0];
        #pragma unroll
        for (int kc = 0; kc < 8; ++kc) {
            const int off = (rlow * 512 + kg * 16 + kc * 64) ^ rswz;  // full-addr XOR
            const short8 ah = *(const short8*)(hbase + off);
            const short8 al = *(const short8*)(lbase + off);
            aHH[0] = __builtin_amdgcn_mfma_f32_16x16x32_bf16(ah, wh[0][kc], aHH[0], 0, 0, 0);
            aHH[1] = __builtin_amdgcn_mfma_f32_16x16x32_bf16(ah, wh[1][kc], aHH[1], 0, 0, 0);
            aHL[0] = __builtin_amdgcn_mfma_f32_16x16x32_bf16(ah, wl[0][kc], aHL[0], 0, 0, 0);
            aHL[1] = __builtin_amdgcn_mfma_f32_16x16x32_bf16(ah, wl[1][kc], aHL[1], 0, 0, 0);
            aLH[0] = __builtin_amdgcn_mfma_f32_16x16x32_bf16(al, wh[0][kc], aLH[0], 0, 0, 0);
            aLH[1] = __builtin_amdgcn_mfma_f32_16x16x32_bf16(al, wh[1][kc], aLH[1], 0, 0, 0);
        }

        // prefetch Bu for t+1 (uniform branch)
        float bu_n[2][4];
        if (t < 255) {
            #pragma unroll
            for (int tile = 0; tile < 2; ++tile)
                #pragma unroll
                for (int q = 0; q < 4; ++q)
                    bu_n[tile][q] = yp[(size_t)(r0 + kg * 4 + q) * 65536
                                       + (size_t)(t + 1) * 256 + (col0 + tile * 16 + rlow)];
        }

        // epilogue: y = acc + bK + Bu ; split hi/lo into buf^1 ; store y
        char* whb = (char*)&cbuf[cur ^ 1][0][0];
        char* wlb = (char*)&cbuf[cur ^ 1][1][0];
        #pragma unroll
        for (int tile = 0; tile < 2; ++tile) {
            const int col = col0 + tile * 16 + rlow;
            #pragma unroll
            for (int q = 0; q < 4; ++q) {
                const int row = kg * 4 + q;
                const float yv = aHH[tile][q] + aHL[tile][q] + aLH[tile][q]
                               + bkv[tile] + bu_c[tile][q];
                const unsigned short hb = f2bf(yv);
                const unsigned short lb = f2bf(yv - bf2f(hb));
                const int byte = (row * 512 + col * 2) ^ ((row & 7) << 4);
                *(unsigned short*)(whb + byte) = hb;
                *(unsigned short*)(wlb + byte) = lb;
                yp[(size_t)(r0 + row) * 65536 + (size_t)t * 256 + col] = yv;
            }
        }
        if (t < 255) {
            #pragma unroll
            for (int tile = 0; tile < 2; ++tile)
                #pragma unroll
                for (int q = 0; q < 4; ++q)
                    bu_c[tile][q] = bu_n[tile][q];
        }
        __syncthreads();
        cur ^= 1;
    }
}

// ---------------------------------------------------------------------------
extern "C" void kernel_launch(void* const* d_in, const int* in_sizes, int n_in,
                              void* d_out, int out_size, void* d_ws, size_t ws_size,
                              hipStream_t stream)
{
    const float* x   = (const float*)d_in[0];
    const float* u   = (const float*)d_in[1];
    const float* Wx1 = (const float*)d_in[2];
    const float* bx1 = (const float*)d_in[3];
    const float* Wx2 = (const float*)d_in[4];
    const float* bx2 = (const float*)d_in[5];
    const float* Wx3 = (const float*)d_in[6];
    const float* Wu1 = (const float*)d_in[7];
    const float* bu1 = (const float*)d_in[8];
    const float* Wu2 = (const float*)d_in[9];
    const float* WB  = (const float*)d_in[10];
    const float* WK  = (const float*)d_in[11];
    const float* bK  = (const float*)d_in[12];

    float* y  = (float*)d_out;                  // output 0
    float* yp = y + (size_t)MM * 256;           // output 1, doubles as bf16 scratch

    char* ws = (char*)d_ws;
    __hip_bfloat16* x_bf = (__hip_bfloat16*)(ws);
    __hip_bfloat16* u_bf = (__hip_bfloat16*)(ws + 16777216);
    __hip_bfloat16* wTb  = (__hip_bfloat16*)(ws + 33554432);
    __hip_bfloat16* Wx1T = wTb;
    __hip_bfloat16* Wx2T = wTb + 16384;
    __hip_bfloat16* Wx3T = wTb + 81920;
    __hip_bfloat16* Wu1T = wTb + 131072;
    __hip_bfloat16* Wu2T = wTb + 147456;
    __hip_bfloat16* WBT  = wTb + 196608;
    __hip_bfloat16* t2   = (__hip_bfloat16*)(ws + 34078720);

    __hip_bfloat16* g1_bf = (__hip_bfloat16*)yp;
    __hip_bfloat16* v1_bf = (__hip_bfloat16*)((char*)yp + 67108864);

    dim3 blk(256);

    // conversions (fused launches)
    conv2_bf16<<<16384, blk, 0, stream>>>(x, u, x_bf, u_bf);
    wtrans_all<<<1024, blk, 0, stream>>>(Wx1, Wx2, Wx3, Wu1, Wu2, WB,
                                         Wx1T, Wx2T, Wx3T, Wu1T, Wu2T, WBT);

    // x path
    mgemm<0><<<dim3(1024, 2), blk, 0, stream>>>(x_bf, 64, nullptr, 0, 64,
        Wx1T, 64, 256, bx1, g1_bf, 256, 0);
    mgemm<0><<<dim3(1024, 2), blk, 0, stream>>>(g1_bf, 256, nullptr, 0, 256,
        Wx2T, 256, 256, bx2, t2, 256, 0);
    mgemm<2><<<dim3(1024, 2), blk, 0, stream>>>(t2, 256, nullptr, 0, 256,
        Wx3T, 256, 192, nullptr, y, 256, 64);
    copy_x<<<(MM * 16) / 256, blk, 0, stream>>>(x, y);

    // u path
    mgemm<0><<<dim3(1024, 2), blk, 0, stream>>>(u_bf, 64, nullptr, 0, 64,
        Wu1T, 64, 256, bu1, v1_bf, 256, 0);
    mgemm<1><<<dim3(1024, 2), blk, 0, stream>>>(v1_bf, 256, nullptr, 0, 256,
        Wu2T, 256, 192, nullptr, t2, 192, 0);
    mgemm<3><<<dim3(1024, 2), blk, 0, stream>>>(u_bf, 64, t2, 192, 64,
        WBT, 256, 256, nullptr, yp, 256, 0);

    // recurrence
    y0copy<<<512, blk, 0, stream>>>(y, yp);
    scan_mfma<<<32, dim3(512), 0, stream>>>(WK, bK, yp);
}